// Round 1
// baseline (548.426 us; speedup 1.0000x reference)
//
#include <hip/hip_runtime.h>
#include <hip/hip_bf16.h>

// ---------------------------------------------------------------------------
// AdaptiveEmbedding: 3-cluster adaptive input embedding.
//   ids in [0,20000)      -> emb0[id] (1024), padding row 0 is zero
//   ids in [20000,60000)  -> proj1(1024x256) @ emb1[id-20000]
//   ids in [60000,128000) -> proj2(1024x64)  @ emb2[id-60000]
// All scaled by sqrt(1024) = 32. Every token belongs to exactly one cluster,
// so out rows are each written exactly once (no pre-zero needed).
//
// Strategy: compact c1/c2 token lists with atomics, then per-cluster bf16
// MFMA GEMM (C[M=32 tokens x N=1024] = E[M x K] * P^T), plus a masked float4
// copy kernel for cluster 0.
// ---------------------------------------------------------------------------

typedef __attribute__((ext_vector_type(4))) float  float4v;
typedef __attribute__((ext_vector_type(8))) short  short8;

#define N_TOK   32768
#define D_MODEL 1024

__device__ __forceinline__ short f2bf(float x) {
    // round-to-nearest-even f32 -> bf16 (inputs are finite)
    unsigned u = __builtin_bit_cast(unsigned, x);
    unsigned r = u + 0x7fffu + ((u >> 16) & 1u);
    return (short)(r >> 16);
}

__device__ __forceinline__ short8 cvt8(float4v a, float4v b) {
    short8 r;
    r[0] = f2bf(a[0]); r[1] = f2bf(a[1]); r[2] = f2bf(a[2]); r[3] = f2bf(a[3]);
    r[4] = f2bf(b[0]); r[5] = f2bf(b[1]); r[6] = f2bf(b[2]); r[7] = f2bf(b[3]);
    return r;
}

// -------------------------- partition ---------------------------------------
__global__ void partition_k(const int* __restrict__ ids, int n,
                            int* __restrict__ cnt,
                            int* __restrict__ l1, int* __restrict__ l2)
{
    int i = blockIdx.x * blockDim.x + threadIdx.x;
    if (i >= n) return;
    int id = ids[i];
    if (id < 20000) return;                    // cluster 0 handled by copy kernel
    if (id < 60000) { int p = atomicAdd(&cnt[0], 1); l1[p] = i; }
    else            { int p = atomicAdd(&cnt[1], 1); l2[p] = i; }
}

// -------------------------- cluster 0 copy ----------------------------------
__global__ __launch_bounds__(256)
void copy_c0(const int* __restrict__ ids, const float* __restrict__ emb0,
             float* __restrict__ out)
{
    int t = blockIdx.x;
    int id = ids[t];
    if (id >= 20000) return;
    // emb0 row 0 is all-zero, so id==0 (padding) needs no special case.
    const float4v* src = (const float4v*)(emb0 + (size_t)id * D_MODEL);
    float4v*       dst = (float4v*)(out + (size_t)t * D_MODEL);
    float4v v = src[threadIdx.x];
    dst[threadIdx.x] = v * 32.0f;              // sqrt(1024)
}

// -------------------------- projected-cluster GEMM --------------------------
// Block: 32 gathered tokens x 1024 dims. 4 waves, wave w owns dims
// [w*256, w*256+256) as 16 MFMA n-tiles of 16. K iterated in steps of 32.
// MFMA 16x16x32 bf16 fragment layouts (verified mappings):
//   A: lane holds A[m = lane&15][k = (lane>>4)*8 + j], j=0..7
//   B: lane holds B[k = (lane>>4)*8 + j][n = lane&15]  (= P[n][k], row-major P)
//   D: acc[reg r] = D[row = (lane>>4)*4 + r][col = lane&15]
template<int K, int START>
__global__ __launch_bounds__(256)
void gemm_proj(const int* __restrict__ ids,
               const float* __restrict__ table,   // [rows, K] fp32
               const float* __restrict__ proj,    // [1024, K] fp32
               const int* __restrict__ list,
               const int* __restrict__ cnt_ptr,
               float* __restrict__ out)
{
    const int count  = *cnt_ptr;
    const int m_base = blockIdx.x * 32;
    if (m_base >= count) return;

    __shared__ int s_tok[32];
    __shared__ int s_loc[32];
    const int tid = threadIdx.x;
    if (tid < 32) {
        int m   = m_base + tid;
        int tok = (m < count) ? list[m] : -1;
        s_tok[tid] = tok;
        s_loc[tid] = (tok >= 0) ? (ids[tok] - START) : 0;
    }
    __syncthreads();

    const int lane = tid & 63;
    const int wave = tid >> 6;     // 0..3
    const int col  = lane & 15;
    const int quad = lane >> 4;    // 0..3

    const float* arow0 = table + (size_t)s_loc[col]      * K + quad * 8;
    const float* arow1 = table + (size_t)s_loc[16 + col] * K + quad * 8;
    const float* bcol  = proj  + (size_t)(wave * 256 + col) * K + quad * 8;

    float4v acc0[16], acc1[16];
#pragma unroll
    for (int i = 0; i < 16; i++) {
        acc0[i] = (float4v){0.f, 0.f, 0.f, 0.f};
        acc1[i] = (float4v){0.f, 0.f, 0.f, 0.f};
    }

#pragma unroll
    for (int ks = 0; ks < K; ks += 32) {
        short8 a0 = cvt8(*(const float4v*)(arow0 + ks),
                         *(const float4v*)(arow0 + ks + 4));
        short8 a1 = cvt8(*(const float4v*)(arow1 + ks),
                         *(const float4v*)(arow1 + ks + 4));
        const float* bp = bcol + ks;
#pragma unroll
        for (int nt = 0; nt < 16; nt++) {
            short8 b = cvt8(*(const float4v*)(bp),
                            *(const float4v*)(bp + 4));
            acc0[nt] = __builtin_amdgcn_mfma_f32_16x16x32_bf16(a0, b, acc0[nt], 0, 0, 0);
            acc1[nt] = __builtin_amdgcn_mfma_f32_16x16x32_bf16(a1, b, acc1[nt], 0, 0, 0);
            bp += 16 * K;
        }
    }

#pragma unroll
    for (int r = 0; r < 4; r++) {
        int row = quad * 4 + r;
        if (m_base + row < count) {
            float* orow = out + (size_t)s_tok[row] * D_MODEL + wave * 256 + col;
#pragma unroll
            for (int nt = 0; nt < 16; nt++) orow[nt * 16] = acc0[nt][r] * 32.0f;
        }
        if (m_base + 16 + row < count) {
            float* orow = out + (size_t)s_tok[16 + row] * D_MODEL + wave * 256 + col;
#pragma unroll
            for (int nt = 0; nt < 16; nt++) orow[nt * 16] = acc1[nt][r] * 32.0f;
        }
    }
}

// ---------------------------------------------------------------------------
extern "C" void kernel_launch(void* const* d_in, const int* in_sizes, int n_in,
                              void* d_out, int out_size, void* d_ws, size_t ws_size,
                              hipStream_t stream)
{
    const int*   ids   = (const int*)  d_in[0];
    const float* emb0  = (const float*)d_in[1];
    const float* emb1  = (const float*)d_in[2];
    const float* emb2  = (const float*)d_in[3];
    const float* proj1 = (const float*)d_in[4];
    const float* proj2 = (const float*)d_in[5];
    float*       out   = (float*)d_out;
    const int n = in_sizes[0];                 // 32768 tokens

    // workspace: [0..8) counters, then two token lists (n ints each)
    int* cnt = (int*)d_ws;
    int* l1  = (int*)((char*)d_ws + 256);
    int* l2  = l1 + n;

    hipMemsetAsync(cnt, 0, 2 * sizeof(int), stream);
    partition_k<<<(n + 255) / 256, 256, 0, stream>>>(ids, n, cnt, l1, l2);
    copy_c0<<<n, 256, 0, stream>>>(ids, emb0, out);
    gemm_proj<256, 20000><<<(n + 31) / 32, 256, 0, stream>>>(ids, emb1, proj1, l1, &cnt[0], out);
    gemm_proj< 64, 60000><<<(n + 31) / 32, 256, 0, stream>>>(ids, emb2, proj2, l2, &cnt[1], out);
}

// Round 2
// 369.208 us; speedup vs baseline: 1.4854x; 1.4854x over previous
//
#include <hip/hip_runtime.h>
#include <hip/hip_bf16.h>

// ---------------------------------------------------------------------------
// AdaptiveEmbedding: 3-cluster adaptive input embedding.
//   ids in [0,20000)      -> emb0[id] (1024), padding row 0 is zero
//   ids in [20000,60000)  -> proj1(1024x256) @ emb1[id-20000]
//   ids in [60000,128000) -> proj2(1024x64)  @ emb2[id-60000]
// All scaled by sqrt(1024) = 32. Every token belongs to exactly one cluster,
// so each out row is written exactly once (no pre-zero needed).
//
// R1 -> R2: partition_k was 225us (41%): 32768 same-address atomics serialize
// at L2. Fixed with ballot/popc wave aggregation (1 atomic/wave/cluster).
// GEMM reshaped to 512 thr / 8 waves x 8 n-tiles: acc 128->64 VGPR,
// 2x wave count for latency hiding.
// ---------------------------------------------------------------------------

typedef __attribute__((ext_vector_type(4))) float  float4v;
typedef __attribute__((ext_vector_type(8))) short  short8;

#define D_MODEL 1024

__device__ __forceinline__ short f2bf(float x) {
    // round-to-nearest-even f32 -> bf16 (inputs are finite)
    unsigned u = __builtin_bit_cast(unsigned, x);
    unsigned r = u + 0x7fffu + ((u >> 16) & 1u);
    return (short)(r >> 16);
}

__device__ __forceinline__ short8 cvt8(float4v a, float4v b) {
    short8 r;
    r[0] = f2bf(a[0]); r[1] = f2bf(a[1]); r[2] = f2bf(a[2]); r[3] = f2bf(a[3]);
    r[4] = f2bf(b[0]); r[5] = f2bf(b[1]); r[6] = f2bf(b[2]); r[7] = f2bf(b[3]);
    return r;
}

// -------------------------- partition (wave-aggregated) ---------------------
__global__ void partition_k(const int* __restrict__ ids, int n,
                            int* __restrict__ cnt,
                            int* __restrict__ l1, int* __restrict__ l2)
{
    int i = blockIdx.x * blockDim.x + threadIdx.x;
    int lane = threadIdx.x & 63;
    int id = (i < n) ? ids[i] : 0;
    bool is1 = (i < n) && (id >= 20000) && (id < 60000);
    bool is2 = (i < n) && (id >= 60000);
    unsigned long long pre = (lane == 63) ? ~0ull : ((1ull << (lane + 1)) - 1ull);
    pre >>= 1;  // bits strictly below `lane`... (built without UB for lane=63)
    // actually simpler: mask of lanes < lane
    unsigned long long ltmask = (lane == 0) ? 0ull : (~0ull >> (64 - lane));

    unsigned long long m1 = __ballot(is1);
    if (m1) {
        int leader = __ffsll((unsigned long long)m1) - 1;
        int base = 0;
        if (lane == leader) base = atomicAdd(&cnt[0], __popcll(m1));
        base = __shfl(base, leader);
        if (is1) l1[base + __popcll(m1 & ltmask)] = i;
    }
    unsigned long long m2 = __ballot(is2);
    if (m2) {
        int leader = __ffsll((unsigned long long)m2) - 1;
        int base = 0;
        if (lane == leader) base = atomicAdd(&cnt[1], __popcll(m2));
        base = __shfl(base, leader);
        if (is2) l2[base + __popcll(m2 & ltmask)] = i;
    }
    (void)pre;
}

// -------------------------- cluster 0 copy ----------------------------------
__global__ __launch_bounds__(256)
void copy_c0(const int* __restrict__ ids, const float* __restrict__ emb0,
             float* __restrict__ out)
{
    int t = blockIdx.x;
    int id = ids[t];
    if (id >= 20000) return;
    // emb0 row 0 is all-zero, so id==0 (padding) needs no special case.
    const float4v* src = (const float4v*)(emb0 + (size_t)id * D_MODEL);
    float4v*       dst = (float4v*)(out + (size_t)t * D_MODEL);
    float4v v = src[threadIdx.x];
    dst[threadIdx.x] = v * 32.0f;              // sqrt(1024)
}

// -------------------------- projected-cluster GEMM --------------------------
// Block: 32 gathered tokens x 1024 dims. 8 waves (512 thr), wave w owns dims
// [w*128, w*128+128) as 8 MFMA n-tiles of 16. K iterated in steps of 32.
// MFMA 16x16x32 bf16 fragment layouts (verified m89 mappings):
//   A: lane holds A[m = lane&15][k = (lane>>4)*8 + j], j=0..7
//   B: lane holds B[k = (lane>>4)*8 + j][n = lane&15]  (= P[n][k], row-major P)
//   D: acc[reg r] = D[row = (lane>>4)*4 + r][col = lane&15]
template<int K, int START>
__global__ __launch_bounds__(512)
void gemm_proj(const int* __restrict__ ids,
               const float* __restrict__ table,   // [rows, K] fp32
               const float* __restrict__ proj,    // [1024, K] fp32
               const int* __restrict__ list,
               const int* __restrict__ cnt_ptr,
               float* __restrict__ out)
{
    const int count  = *cnt_ptr;
    const int m_base = blockIdx.x * 32;
    if (m_base >= count) return;

    __shared__ int s_tok[32];
    __shared__ int s_loc[32];
    const int tid = threadIdx.x;
    if (tid < 32) {
        int m   = m_base + tid;
        int tok = (m < count) ? list[m] : -1;
        s_tok[tid] = tok;
        s_loc[tid] = (tok >= 0) ? (ids[tok] - START) : 0;
    }
    __syncthreads();

    const int lane = tid & 63;
    const int wave = tid >> 6;     // 0..7
    const int col  = lane & 15;
    const int quad = lane >> 4;    // 0..3

    const float* arow0 = table + (size_t)s_loc[col]      * K + quad * 8;
    const float* arow1 = table + (size_t)s_loc[16 + col] * K + quad * 8;
    const float* bcol  = proj  + (size_t)(wave * 128 + col) * K + quad * 8;

    float4v acc0[8], acc1[8];
#pragma unroll
    for (int i = 0; i < 8; i++) {
        acc0[i] = (float4v){0.f, 0.f, 0.f, 0.f};
        acc1[i] = (float4v){0.f, 0.f, 0.f, 0.f};
    }

#pragma unroll
    for (int ks = 0; ks < K; ks += 32) {
        short8 a0 = cvt8(*(const float4v*)(arow0 + ks),
                         *(const float4v*)(arow0 + ks + 4));
        short8 a1 = cvt8(*(const float4v*)(arow1 + ks),
                         *(const float4v*)(arow1 + ks + 4));
        const float* bp = bcol + ks;
#pragma unroll
        for (int nt = 0; nt < 8; nt++) {
            short8 b = cvt8(*(const float4v*)(bp),
                            *(const float4v*)(bp + 4));
            acc0[nt] = __builtin_amdgcn_mfma_f32_16x16x32_bf16(a0, b, acc0[nt], 0, 0, 0);
            acc1[nt] = __builtin_amdgcn_mfma_f32_16x16x32_bf16(a1, b, acc1[nt], 0, 0, 0);
            bp += 16 * K;
        }
    }

#pragma unroll
    for (int r = 0; r < 4; r++) {
        int row = quad * 4 + r;
        if (m_base + row < count) {
            float* orow = out + (size_t)s_tok[row] * D_MODEL + wave * 128 + col;
#pragma unroll
            for (int nt = 0; nt < 8; nt++) orow[nt * 16] = acc0[nt][r] * 32.0f;
        }
        if (m_base + 16 + row < count) {
            float* orow = out + (size_t)s_tok[16 + row] * D_MODEL + wave * 128 + col;
#pragma unroll
            for (int nt = 0; nt < 8; nt++) orow[nt * 16] = acc1[nt][r] * 32.0f;
        }
    }
}

// ---------------------------------------------------------------------------
extern "C" void kernel_launch(void* const* d_in, const int* in_sizes, int n_in,
                              void* d_out, int out_size, void* d_ws, size_t ws_size,
                              hipStream_t stream)
{
    const int*   ids   = (const int*)  d_in[0];
    const float* emb0  = (const float*)d_in[1];
    const float* emb1  = (const float*)d_in[2];
    const float* emb2  = (const float*)d_in[3];
    const float* proj1 = (const float*)d_in[4];
    const float* proj2 = (const float*)d_in[5];
    float*       out   = (float*)d_out;
    const int n = in_sizes[0];                 // 32768 tokens

    // workspace: [0..256) counters, then two token lists (n ints each)
    int* cnt = (int*)d_ws;
    int* l1  = (int*)((char*)d_ws + 256);
    int* l2  = l1 + n;

    hipMemsetAsync(cnt, 0, 2 * sizeof(int), stream);
    partition_k<<<(n + 255) / 256, 256, 0, stream>>>(ids, n, cnt, l1, l2);
    copy_c0<<<n, 256, 0, stream>>>(ids, emb0, out);
    gemm_proj<256, 20000><<<(n + 31) / 32, 512, 0, stream>>>(ids, emb1, proj1, l1, &cnt[0], out);
    gemm_proj< 64, 60000><<<(n + 31) / 32, 512, 0, stream>>>(ids, emb2, proj2, l2, &cnt[1], out);
}

// Round 3
// 310.412 us; speedup vs baseline: 1.7668x; 1.1894x over previous
//
#include <hip/hip_runtime.h>
#include <hip/hip_bf16.h>

// ---------------------------------------------------------------------------
// AdaptiveEmbedding: 3-cluster adaptive input embedding.
//   ids in [0,20000)      -> emb0[id] (1024), padding row 0 is zero
//   ids in [20000,60000)  -> proj1(1024x256) @ emb1[id-20000]
//   ids in [60000,128000) -> proj2(1024x64)  @ emb2[id-60000]
// Scaled by sqrt(1024)=32. Each out row written exactly once.
//
// R2 -> R3: gemm_proj was 114us with VGPR=68, MfmaUtil 1.8%, VALUBusy 6.6%
// -> pure load-latency serialization caused by fp32 B fetch (2 float4 loads +
// ~25 VALU cvt per fragment, per lane, per k-step). Fix: pre-convert projs to
// bf16 in ws (fused into partition kernel as extra blocks); B fragment is now
// ONE 16-B load, no cvt. copy_c0 now uses a compacted cluster-0 list +
// grid-stride instead of 32768 mostly-dead blocks.
// ---------------------------------------------------------------------------

typedef __attribute__((ext_vector_type(4))) float        float4v;
typedef __attribute__((ext_vector_type(8))) short        short8;
typedef __attribute__((ext_vector_type(2))) unsigned int uint2v;

#define D_MODEL 1024

__device__ __forceinline__ short f2bf(float x) {
    // round-to-nearest-even f32 -> bf16 (inputs are finite)
    unsigned u = __builtin_bit_cast(unsigned, x);
    unsigned r = u + 0x7fffu + ((u >> 16) & 1u);
    return (short)(r >> 16);
}

__device__ __forceinline__ short8 cvt8(float4v a, float4v b) {
    short8 r;
    r[0] = f2bf(a[0]); r[1] = f2bf(a[1]); r[2] = f2bf(a[2]); r[3] = f2bf(a[3]);
    r[4] = f2bf(b[0]); r[5] = f2bf(b[1]); r[6] = f2bf(b[2]); r[7] = f2bf(b[3]);
    return r;
}

__device__ __forceinline__ uint2v pack4(float4v v) {
    uint2v r;
    r[0] = (unsigned)(unsigned short)f2bf(v[0]) | ((unsigned)(unsigned short)f2bf(v[1]) << 16);
    r[1] = (unsigned)(unsigned short)f2bf(v[2]) | ((unsigned)(unsigned short)f2bf(v[3]) << 16);
    return r;
}

// ------------------ partition (3 lists) + proj->bf16 conversion -------------
// blocks [0, pb)            : wave-aggregated partition of ids into l0/l1/l2
// blocks [pb, pb+256)       : proj1 (1024x256 fp32) -> bf16, 1 float4/thread
// blocks [pb+256, pb+320)   : proj2 (1024x64  fp32) -> bf16
__global__ __launch_bounds__(256)
void prep_k(const int* __restrict__ ids, int n, int pb,
            int* __restrict__ cnt,
            int* __restrict__ l0, int* __restrict__ l1, int* __restrict__ l2,
            const float* __restrict__ proj1, const float* __restrict__ proj2,
            uint2v* __restrict__ p1bf, uint2v* __restrict__ p2bf)
{
    const int b = blockIdx.x;
    if (b >= pb) {
        if (b < pb + 256) {
            int t = (b - pb) * 256 + threadIdx.x;          // 65536 float4s
            p1bf[t] = pack4(((const float4v*)proj1)[t]);
        } else {
            int t = (b - pb - 256) * 256 + threadIdx.x;    // 16384 float4s
            p2bf[t] = pack4(((const float4v*)proj2)[t]);
        }
        return;
    }
    int i = b * blockDim.x + threadIdx.x;
    int lane = threadIdx.x & 63;
    int id = (i < n) ? ids[i] : -1;
    bool is0 = (i < n) && (id < 20000);
    bool is1 = (i < n) && (id >= 20000) && (id < 60000);
    bool is2 = (i < n) && (id >= 60000);
    unsigned long long ltmask = (lane == 0) ? 0ull : (~0ull >> (64 - lane));

    unsigned long long m;
    m = __ballot(is0);
    if (m) {
        int leader = __ffsll(m) - 1;
        int base = 0;
        if (lane == leader) base = atomicAdd(&cnt[2], __popcll(m));
        base = __shfl(base, leader);
        if (is0) l0[base + __popcll(m & ltmask)] = i;
    }
    m = __ballot(is1);
    if (m) {
        int leader = __ffsll(m) - 1;
        int base = 0;
        if (lane == leader) base = atomicAdd(&cnt[0], __popcll(m));
        base = __shfl(base, leader);
        if (is1) l1[base + __popcll(m & ltmask)] = i;
    }
    m = __ballot(is2);
    if (m) {
        int leader = __ffsll(m) - 1;
        int base = 0;
        if (lane == leader) base = atomicAdd(&cnt[1], __popcll(m));
        base = __shfl(base, leader);
        if (is2) l2[base + __popcll(m & ltmask)] = i;
    }
}

// -------------------------- cluster 0 copy (grid-stride over l0) ------------
__global__ __launch_bounds__(256)
void copy_c0(const int* __restrict__ ids, const int* __restrict__ l0,
             const int* __restrict__ cnt,
             const float* __restrict__ emb0, float* __restrict__ out)
{
    const int count0 = cnt[2];
    for (int b = blockIdx.x; b < count0; b += gridDim.x) {
        int t = l0[b];
        int id = ids[t];   // emb0 row 0 is all-zero -> padding needs no special case
        const float4v* src = (const float4v*)(emb0 + (size_t)id * D_MODEL);
        float4v*       dst = (float4v*)(out + (size_t)t * D_MODEL);
        dst[threadIdx.x] = src[threadIdx.x] * 32.0f;   // sqrt(1024)
    }
}

// -------------------------- projected-cluster GEMM --------------------------
// Block: 32 gathered tokens x 1024 dims, 8 waves (512 thr). Wave w owns dims
// [w*128, w*128+128) as 8 MFMA n-tiles. A gathered fp32->bf16 on the fly
// (2 loads + 1 cvt8 per 16-row half per k-step); B is pre-converted bf16:
// one 16-B global load per fragment, L2-resident (proj1bf=512KB, proj2bf=128KB).
// MFMA 16x16x32 bf16 fragment layouts (verified m89 mappings):
//   A: lane holds A[m = lane&15][k = (lane>>4)*8 + j], j=0..7
//   B: lane holds B[k = (lane>>4)*8 + j][n = lane&15]  (= P[n][k], row-major P)
//   D: acc[reg r] = D[row = (lane>>4)*4 + r][col = lane&15]
template<int K, int START>
__global__ __launch_bounds__(512)
void gemm_proj(const int* __restrict__ ids,
               const float* __restrict__ table,   // [rows, K] fp32
               const short* __restrict__ pbf,     // [1024, K] bf16
               const int* __restrict__ list,
               const int* __restrict__ cnt_ptr,
               float* __restrict__ out)
{
    const int count  = *cnt_ptr;
    const int m_base = blockIdx.x * 32;
    if (m_base >= count) return;

    __shared__ int s_tok[32];
    __shared__ int s_loc[32];
    const int tid = threadIdx.x;
    if (tid < 32) {
        int m   = m_base + tid;
        int tok = (m < count) ? list[m] : -1;
        s_tok[tid] = tok;
        s_loc[tid] = (tok >= 0) ? (ids[tok] - START) : 0;
    }
    __syncthreads();

    const int lane = tid & 63;
    const int wave = tid >> 6;     // 0..7
    const int col  = lane & 15;
    const int quad = lane >> 4;    // 0..3

    const float* arow0 = table + (size_t)s_loc[col]      * K + quad * 8;
    const float* arow1 = table + (size_t)s_loc[16 + col] * K + quad * 8;
    const short* bbase = pbf   + (size_t)(wave * 128 + col) * K + quad * 8;

    float4v acc0[8], acc1[8];
#pragma unroll
    for (int i = 0; i < 8; i++) {
        acc0[i] = (float4v){0.f, 0.f, 0.f, 0.f};
        acc1[i] = (float4v){0.f, 0.f, 0.f, 0.f};
    }

#pragma unroll
    for (int ks = 0; ks < K; ks += 32) {
        short8 a0 = cvt8(*(const float4v*)(arow0 + ks),
                         *(const float4v*)(arow0 + ks + 4));
        short8 a1 = cvt8(*(const float4v*)(arow1 + ks),
                         *(const float4v*)(arow1 + ks + 4));
#pragma unroll
        for (int nt = 0; nt < 8; nt++) {
            short8 b = *(const short8*)(bbase + (size_t)nt * 16 * K + ks);
            acc0[nt] = __builtin_amdgcn_mfma_f32_16x16x32_bf16(a0, b, acc0[nt], 0, 0, 0);
            acc1[nt] = __builtin_amdgcn_mfma_f32_16x16x32_bf16(a1, b, acc1[nt], 0, 0, 0);
        }
    }

#pragma unroll
    for (int r = 0; r < 4; r++) {
        int row = quad * 4 + r;
        if (m_base + row < count) {
            float* orow = out + (size_t)s_tok[row] * D_MODEL + wave * 128 + col;
#pragma unroll
            for (int nt = 0; nt < 8; nt++) orow[nt * 16] = acc0[nt][r] * 32.0f;
        }
        if (m_base + 16 + row < count) {
            float* orow = out + (size_t)s_tok[16 + row] * D_MODEL + wave * 128 + col;
#pragma unroll
            for (int nt = 0; nt < 8; nt++) orow[nt * 16] = acc1[nt][r] * 32.0f;
        }
    }
}

// ---------------------------------------------------------------------------
extern "C" void kernel_launch(void* const* d_in, const int* in_sizes, int n_in,
                              void* d_out, int out_size, void* d_ws, size_t ws_size,
                              hipStream_t stream)
{
    const int*   ids   = (const int*)  d_in[0];
    const float* emb0  = (const float*)d_in[1];
    const float* emb1  = (const float*)d_in[2];
    const float* emb2  = (const float*)d_in[3];
    const float* proj1 = (const float*)d_in[4];
    const float* proj2 = (const float*)d_in[5];
    float*       out   = (float*)d_out;
    const int n = in_sizes[0];                 // 32768 tokens

    // ws layout: [0,256) counters | l0,l1,l2 (n ints each) | proj1bf | proj2bf
    int*   cnt  = (int*)d_ws;
    int*   l0   = (int*)((char*)d_ws + 256);
    int*   l1   = l0 + n;
    int*   l2   = l1 + n;
    size_t poff = (256 + (size_t)3 * n * 4 + 255) & ~(size_t)255;
    short* p1bf = (short*)((char*)d_ws + poff);
    short* p2bf = p1bf + 1024 * 256;

    const int pb = (n + 255) / 256;            // partition blocks

    hipMemsetAsync(cnt, 0, 4 * sizeof(int), stream);
    prep_k<<<pb + 256 + 64, 256, 0, stream>>>(ids, n, pb, cnt, l0, l1, l2,
                                              proj1, proj2,
                                              (uint2v*)p1bf, (uint2v*)p2bf);
    copy_c0<<<2048, 256, 0, stream>>>(ids, l0, cnt, emb0, out);
    gemm_proj<256, 20000><<<(n + 31) / 32, 512, 0, stream>>>(ids, emb1, p1bf, l1, &cnt[0], out);
    gemm_proj< 64, 60000><<<(n + 31) / 32, 512, 0, stream>>>(ids, emb2, p2bf, l2, &cnt[1], out);
}